// Round 1
// baseline (1460.785 us; speedup 1.0000x reference)
//
#include <hip/hip_runtime.h>
#include <math.h>

#define T_  4
#define L_  4
#define N_  2048
#define E_  65536
#define H_  64
#define CAP 128   // max edges bucketed per target node (mean 32, Poisson tail << CAP)

// ---------------------------------------------------------------------------
// Workspace layout (d_ws):
//   int   cnt[T*N]              @ byte 0        (32 KB)
//   int   bucket[T*N*CAP]       @ byte 32768    (4 MB)
//   float val[T*2*L*N]          @ byte 4227072  (256 KB, 16B-aligned)
// ---------------------------------------------------------------------------

__device__ __forceinline__ float wave_sum64(float v) {
#pragma unroll
    for (int off = 32; off; off >>= 1) v += __shfl_xor(v, off, 64);
    return v;
}

__global__ void zero_cnt_kernel(int* __restrict__ cnt) {
    int i = blockIdx.x * blockDim.x + threadIdx.x;
    if (i < T_ * N_) cnt[i] = 0;
}

__global__ void count_fill_kernel(const int* __restrict__ tgt_idx,
                                  int* __restrict__ cnt,
                                  int* __restrict__ bucket) {
    int g = blockIdx.x * blockDim.x + threadIdx.x;   // 0 .. T*E-1
    if (g >= T_ * E_) return;
    int t = g >> 16;              // E = 65536
    int e = g & (E_ - 1);
    int tgt = tgt_idx[g];
    int slot = atomicAdd(&cnt[t * N_ + tgt], 1);
    if (slot < CAP) bucket[(t * N_ + tgt) * CAP + slot] = e;
}

// One wave per (type, node). lane = head dim h (0..63).
// Computes q/k/v/e for all 4 layers, online softmax over the node's edge
// bucket, skip connection, then P/Q half-wave sums into val.
__global__ __launch_bounds__(256) void attn_kernel(
    const float* __restrict__ x,        // [T*N*2]
    const float* __restrict__ ea,       // [T*E*2]
    const int*   __restrict__ src_idx,  // [T*E]
    const float* __restrict__ Wq, const float* __restrict__ bq,
    const float* __restrict__ Wk, const float* __restrict__ bk,
    const float* __restrict__ Wv, const float* __restrict__ bv,
    const float* __restrict__ We,
    const float* __restrict__ Wsk, const float* __restrict__ bsk,
    const int*   __restrict__ cnt,
    const int*   __restrict__ bucket,
    float* __restrict__ val)            // [T * 2*L*N]
{
    int wid  = (blockIdx.x * blockDim.x + threadIdx.x) >> 6;  // 0 .. T*N-1
    int lane = threadIdx.x & 63;
    int t = wid >> 11;            // N = 2048
    int n = wid & (N_ - 1);

    // Per-lane weights for all layers (lane = h).
    float wq0[L_], wq1[L_], bqv[L_];
    float wk0[L_], wk1[L_], bkv[L_];
    float wv0[L_], wv1[L_], bvv[L_];
    float we0[L_], we1[L_];
    float ws0[L_], ws1[L_], bsv[L_];
#pragma unroll
    for (int l = 0; l < L_; ++l) {
        int tl  = t * L_ + l;
        int o0  = (tl * 2 + 0) * H_ + lane;
        int o1  = (tl * 2 + 1) * H_ + lane;
        int ob  = tl * H_ + lane;
        wq0[l] = Wq[o0];  wq1[l] = Wq[o1];  bqv[l] = bq[ob];
        wk0[l] = Wk[o0];  wk1[l] = Wk[o1];  bkv[l] = bk[ob];
        wv0[l] = Wv[o0];  wv1[l] = Wv[o1];  bvv[l] = bv[ob];
        we0[l] = We[o0];  we1[l] = We[o1];
        ws0[l] = Wsk[o0]; ws1[l] = Wsk[o1]; bsv[l] = bsk[ob];
    }

    float x0 = x[(t * N_ + n) * 2 + 0];
    float x1 = x[(t * N_ + n) * 2 + 1];

    float qv[L_];
#pragma unroll
    for (int l = 0; l < L_; ++l)
        qv[l] = fmaf(x0, wq0[l], fmaf(x1, wq1[l], bqv[l]));

    float m[L_], s[L_], acc[L_];
#pragma unroll
    for (int l = 0; l < L_; ++l) { m[l] = -INFINITY; s[l] = 0.f; acc[l] = 0.f; }

    int base  = (t * N_ + n) * CAP;
    int cnt_n = cnt[t * N_ + n];
    if (cnt_n > CAP) cnt_n = CAP;

    for (int j = 0; j < cnt_n; ++j) {
        int e   = bucket[base + j];
        int src = src_idx[t * E_ + e];          // in [0, T*N)
        float xs0 = x[src * 2 + 0];
        float xs1 = x[src * 2 + 1];
        float ea0 = ea[(t * E_ + e) * 2 + 0];
        float ea1 = ea[(t * E_ + e) * 2 + 1];

#pragma unroll
        for (int l = 0; l < L_; ++l) {
            float eh = fmaf(x0 * 0.f, 0.f, fmaf(ea0, we0[l], ea1 * we1[l]));
            float kh = fmaf(xs0, wk0[l], fmaf(xs1, wk1[l], bkv[l])) + eh;
            float vh = fmaf(xs0, wv0[l], fmaf(xs1, wv1[l], bvv[l])) + eh;
            float alpha = wave_sum64(qv[l] * kh) * 0.125f;  // 1/sqrt(64)
            // online softmax update (uniform across lanes)
            float mn   = fmaxf(m[l], alpha);
            float corr = __expf(m[l] - mn);     // exp(-inf) = 0 on first edge
            float w    = __expf(alpha - mn);
            s[l]   = fmaf(s[l], corr, w);
            acc[l] = fmaf(acc[l], corr, w * vh);
            m[l]   = mn;
        }
    }

    // Epilogue: msg/s + skip, then half-wave P/Q sums.
#pragma unroll
    for (int l = 0; l < L_; ++l) {
        float o = acc[l] / (s[l] + 1e-16f)
                + fmaf(x0, ws0[l], fmaf(x1, ws1[l], bsv[l]));
        float p = o;
#pragma unroll
        for (int off = 16; off; off >>= 1) p += __shfl_xor(p, off, 64);
        // lane 0 holds sum over h<32 (P), lane 32 holds sum over h>=32 (Q)
        int row = l * N_ + n;
        if (lane == 0)  val[t * (2 * L_ * N_) + row * 2 + 0] = p;
        if (lane == 32) val[t * (2 * L_ * N_) + row * 2 + 1] = p;
    }
}

// One wave per output row: y[t,r] = Wfc[t,r,:] . val[t,:] + bfc[t,r]
__global__ __launch_bounds__(256) void fc_kernel(
    const float* __restrict__ Wfc,   // [T,4096,16384]
    const float* __restrict__ bfc,   // [T,4096]
    const float* __restrict__ val,   // [T,16384]
    float* __restrict__ out)         // [T*4096] == (T,N,2) flat
{
    int wid  = (blockIdx.x * blockDim.x + threadIdx.x) >> 6;  // 0..16383
    int lane = threadIdx.x & 63;
    int t = wid >> 12;                                         // 4096 rows/type

    const float4* wrow = (const float4*)(Wfc + (size_t)wid * 16384);
    const float4* v4   = (const float4*)(val + t * 16384);

    float a0 = 0.f, a1 = 0.f, a2 = 0.f, a3 = 0.f;
#pragma unroll 4
    for (int it = 0; it < 64; ++it) {
        float4 w = wrow[it * 64 + lane];
        float4 v = v4[it * 64 + lane];
        a0 = fmaf(w.x, v.x, a0);
        a1 = fmaf(w.y, v.y, a1);
        a2 = fmaf(w.z, v.z, a2);
        a3 = fmaf(w.w, v.w, a3);
    }
    float acc = wave_sum64((a0 + a1) + (a2 + a3));
    if (lane == 0) out[wid] = acc + bfc[wid];
}

extern "C" void kernel_launch(void* const* d_in, const int* in_sizes, int n_in,
                              void* d_out, int out_size, void* d_ws, size_t ws_size,
                              hipStream_t stream) {
    const float* x    = (const float*)d_in[0];
    const float* ea   = (const float*)d_in[1];
    const int*   src  = (const int*)  d_in[2];
    const int*   tgt  = (const int*)  d_in[3];
    const float* Wq   = (const float*)d_in[4];
    const float* bq   = (const float*)d_in[5];
    const float* Wk   = (const float*)d_in[6];
    const float* bk   = (const float*)d_in[7];
    const float* Wv   = (const float*)d_in[8];
    const float* bv   = (const float*)d_in[9];
    const float* We   = (const float*)d_in[10];
    const float* Wsk  = (const float*)d_in[11];
    const float* bsk  = (const float*)d_in[12];
    const float* Wfc  = (const float*)d_in[13];
    const float* bfc  = (const float*)d_in[14];
    float* out = (float*)d_out;

    int*   cnt    = (int*)d_ws;
    int*   bucket = cnt + T_ * N_;
    float* val    = (float*)(bucket + (size_t)T_ * N_ * CAP);

    zero_cnt_kernel<<<(T_ * N_ + 255) / 256, 256, 0, stream>>>(cnt);
    count_fill_kernel<<<(T_ * E_ + 255) / 256, 256, 0, stream>>>(tgt, cnt, bucket);
    // T*N waves, 4 waves per 256-thread block
    attn_kernel<<<(T_ * N_) / 4, 256, 0, stream>>>(
        x, ea, src, Wq, bq, Wk, bk, Wv, bv, We, Wsk, bsk, cnt, bucket, val);
    // T*4096 rows, 4 waves per block
    fc_kernel<<<(T_ * 4096) / 4, 256, 0, stream>>>(Wfc, bfc, val, out);
}